// Round 9
// baseline (545.241 us; speedup 1.0000x reference)
//
#include <hip/hip_runtime.h>

#define NN 50000
#define EE 800000
#define INCH 256
#define D 64
#define ED 16
#define NC 8
#define NB 196          // scan blocks: 196*256 = 50176 >= NN
#define NEGINF (-3.0e38f)

// fallback scratch (need ~32 MB)
__device__ __align__(16) char g_ws[64u << 20];

typedef __attribute__((ext_vector_type(8))) short bf16x8;
typedef __attribute__((ext_vector_type(4))) float f32x4;

__device__ __forceinline__ unsigned short f2b(float f){
  unsigned u = __float_as_uint(f);
  return (unsigned short)((u + 0x7fffu + ((u >> 16) & 1u)) >> 16);
}
__device__ __forceinline__ unsigned packbf(float lo, float hi){
  return (unsigned)f2b(lo) | ((unsigned)f2b(hi) << 16);
}
__device__ __forceinline__ float blo(unsigned w){ return __uint_as_float(w << 16); }
__device__ __forceinline__ float bhi(unsigned w){ return __uint_as_float(w & 0xffff0000u); }

union FragU { unsigned u[4]; uint4 q; bf16x8 b; };
__device__ __forceinline__ bf16x8 as_frag(unsigned a, unsigned b, unsigned c, unsigned d){
  FragU t; t.u[0]=a; t.u[1]=b; t.u[2]=c; t.u[3]=d; return t.b;
}
__device__ __forceinline__ bf16x8 ld_frag(const unsigned* p){
  FragU t; t.q = *(const uint4*)p; return t.b;
}
// split a,b into bf16 hi-word + bf16 lo(residual)-word
__device__ __forceinline__ void split2(float a, float b, unsigned &hi, unsigned &lo){
  hi = packbf(a, b);
  lo = packbf(a - blo(hi), b - bhi(hi));
}
__device__ __forceinline__ void mk_frags(float4 e0, float4 e1, bf16x8 &Ah, bf16x8 &Al){
  unsigned h0,h1,h2,h3,l0,l1,l2,l3;
  split2(e0.x, e0.y, h0, l0);
  split2(e0.z, e0.w, h1, l1);
  split2(e1.x, e1.y, h2, l2);
  split2(e1.z, e1.w, h3, l3);
  Ah = as_frag(h0,h1,h2,h3);
  Al = as_frag(l0,l1,l2,l3);
}

// ---------------- K0: zero cnt/fill/epc (harness-named kernel) --------------
__global__ __launch_bounds__(256) void Adapter_30872224923942_kernel(
    unsigned* __restrict__ ws, int nwords)
{
  int stride = gridDim.x * 256;
  for (int i = blockIdx.x * 256 + threadIdx.x; i < nwords; i += stride)
    ws[i] = 0u;
}

// ---------------- kpre: weight folds + bf16 packs ---------------------------
__global__ __launch_bounds__(256) void kpre(
    const float* __restrict__ Wq, const float* __restrict__ bq,
    const float* __restrict__ Wk, const float* __restrict__ bk,
    const float* __restrict__ Wv, const float* __restrict__ bv,
    const float* __restrict__ Wo, const float* __restrict__ Wd,
    const float* __restrict__ Wu, const float* __restrict__ Wt,
    float* __restrict__ cvec, float* __restrict__ u,
    float* __restrict__ s0, float* __restrict__ Wvo, float* __restrict__ bvo,
    unsigned* __restrict__ WdTP, unsigned* __restrict__ WuP,
    unsigned* __restrict__ MThP, unsigned* __restrict__ MTlP,
    unsigned* __restrict__ WtTPh, unsigned* __restrict__ WtTPl)
{
  int b = blockIdx.x, t = threadIdx.x;
  if (b < 16){
    int i = b*4 + (t >> 6), j = t & 63;
    float acc = 0.0f;
    for (int d = 0; d < D; ++d) acc = fmaf(Wv[i*D+d], Wo[d*D+j], acc);
    Wvo[i*D+j] = acc;
  } else if (b < 20){
    // WdTP[col*128 + kw] = (Wd[2kw][col], Wd[2kw+1][col])
    for (int k = 0; k < 8; ++k){
      int idx = (b-16)*2048 + t*8 + k;
      int col = idx >> 7, kw = idx & 127;
      WdTP[idx] = packbf(Wd[(2*kw)*D + col], Wd[(2*kw+1)*D + col]);
    }
  } else if (b < 24){
    for (int k = 0; k < 8; ++k){
      int idx = (b-20)*2048 + t*8 + k;
      int d2 = idx >> 8, c = idx & 255;
      WuP[idx] = packbf(Wu[(2*d2)*INCH + c], Wu[(2*d2+1)*INCH + c]);
    }
  } else if (b < 26){
    // M[i][j] = Wq[i]·Wk[j]; MT packed along k at fixed col j, split hi/lo
    for (int k = 0; k < 4; ++k){
      int idx = (b-24)*1024 + t*4 + k;
      int j = idx >> 5, kw = idx & 31;
      float m0 = 0.0f, m1 = 0.0f;
      for (int d = 0; d < D; ++d) m0 = fmaf(Wq[(2*kw  )*D+d], Wk[j*D+d], m0);
      for (int d = 0; d < D; ++d) m1 = fmaf(Wq[(2*kw+1)*D+d], Wk[j*D+d], m1);
      unsigned hi = packbf(m0, m1);
      MThP[idx] = hi;
      MTlP[idx] = packbf(m0 - blo(hi), m1 - bhi(hi));
    }
  } else if (b < 27){
    // WtTP[col*16 + kw]: (Wt[2kw][col], Wt[2kw+1][col]) split; kw 8..15 = 0
    for (int k = 0; k < 4; ++k){
      int idx = t*4 + k;               // 1024 entries
      int col = idx >> 4, kw = idx & 15;
      unsigned hi = 0u, lo = 0u;
      if (kw < 8) split2(Wt[(2*kw)*D + col], Wt[(2*kw+1)*D + col], hi, lo);
      WtTPh[idx] = hi;
      WtTPl[idx] = lo;
    }
  } else {
    if (t < 64){
      float acc = 0.0f;
      for (int d = 0; d < D; ++d) acc = fmaf(Wk[t*D+d], bq[d], acc);
      cvec[t] = acc;
    } else if (t < 128){
      int i = t - 64; float acc = 0.0f;
      for (int d = 0; d < D; ++d) acc = fmaf(Wq[i*D+d], bk[d], acc);
      u[i] = acc;
    } else if (t < 192){
      int j = t - 128; float acc = 0.0f;
      for (int d = 0; d < D; ++d) acc = fmaf(bv[d], Wo[d*D+j], acc);
      bvo[j] = acc;
    } else if (t == 192){
      float acc = 0.0f;
      for (int d = 0; d < D; ++d) acc = fmaf(bq[d], bk[d], acc);
      s0[0] = acc;
    }
  }
}

// ---------------- P1: histogram of src --------------------------------------
__global__ __launch_bounds__(256) void p1_hist(
    const int* __restrict__ eidx, int* __restrict__ cnt)
{
  int e = blockIdx.x * 256 + threadIdx.x;
  if (e < EE) atomicAdd(&cnt[eidx[e]], 1);
}

// ---------------- S1..S3: exclusive scan ------------------------------------
__global__ __launch_bounds__(256) void s1_scan(
    const int* __restrict__ cnt, int* __restrict__ rowptr, int* __restrict__ bsum)
{
  __shared__ int s[256];
  int t = threadIdx.x;
  int i = blockIdx.x * 256 + t;
  int v = (i < NN) ? cnt[i] : 0;
  s[t] = v; __syncthreads();
  #pragma unroll
  for (int off = 1; off < 256; off <<= 1){
    int add = (t >= off) ? s[t - off] : 0;
    __syncthreads();
    s[t] += add;
    __syncthreads();
  }
  if (i < NN) rowptr[i] = s[t] - v;
  if (t == 255) bsum[blockIdx.x] = s[255];
}
__global__ __launch_bounds__(256) void s2_scan(int* __restrict__ bsum)
{
  __shared__ int s[256];
  int t = threadIdx.x;
  int v = (t < NB) ? bsum[t] : 0;
  s[t] = v; __syncthreads();
  #pragma unroll
  for (int off = 1; off < 256; off <<= 1){
    int add = (t >= off) ? s[t - off] : 0;
    __syncthreads();
    s[t] += add;
    __syncthreads();
  }
  if (t < NB) bsum[t] = s[t] - v;
}
__global__ __launch_bounds__(256) void s3_add(
    int* __restrict__ rowptr, const int* __restrict__ bsum)
{
  int i = blockIdx.x * 256 + threadIdx.x;
  if (i < NN) rowptr[i] += bsum[blockIdx.x];
  if (i == 0) rowptr[NN] = EE;
}

// ---------------- P2: build CSR pair list (the one amplified scatter) -------
__global__ __launch_bounds__(256) void p2_build(
    const int* __restrict__ eidx, const int* __restrict__ rowptr,
    int* __restrict__ fill, int2* __restrict__ pairS)
{
  int e = blockIdx.x * 256 + threadIdx.x;
  if (e >= EE) return;
  int src = eidx[e];
  int r = atomicAdd(&fill[src], 1);
  int2 pr; pr.x = e; pr.y = src;
  pairS[rowptr[src] + r] = pr;
}

// ---------------- K1: nf = relu(x@Wd+bd) -> qkH = bf16(nf@M+cvec), qb -------
// v3 (validated round 4): MFMA with split-bf16 on both operands.
__global__ __launch_bounds__(256) void k1_node(
    const float* __restrict__ x, const unsigned* __restrict__ WdTP,
    const float* __restrict__ bd,
    const unsigned* __restrict__ MThP, const unsigned* __restrict__ MTlP,
    const float* __restrict__ cvec, const float* __restrict__ u,
    const float* __restrict__ s0p,
    unsigned short* __restrict__ qkH, float* __restrict__ qb)
{
  __shared__ unsigned sWdT[8192];     // 32 KB [64 col][128 kw], xor-swizzled
  __shared__ unsigned sMTh[2048];     // 8 KB [64 col][32 kw], xor-swizzled
  __shared__ unsigned sMTl[2048];     // 8 KB
  __shared__ float sNf[4][16][68];    // 17 KB nf tile
  int t = threadIdx.x;
  int lane = t & 63;
  int w = t >> 6;
  int colA = lane & 15;               // A row / C col within tile
  int g = lane >> 4;                  // k-group
  int row0 = blockIdx.x * 64 + w * 16;

  int arow = row0 + colA;
  const float* xp = x + (size_t)min(arow, NN-1) * INCH + (g << 3);
  float4 xv[16];
  #pragma unroll
  for (int s = 0; s < 8; ++s){
    xv[2*s  ] = ((const float4*)(xp + s*32))[0];
    xv[2*s+1] = ((const float4*)(xp + s*32))[1];
  }
  #pragma unroll
  for (int i = 0; i < 8; ++i){
    int idx = 4*(t + 256*i);
    int col = idx >> 7;
    int dst = (idx & ~127) | ((idx & 127) ^ ((col & 7) << 2));
    *(uint4*)&sWdT[dst] = ((const uint4*)WdTP)[t + 256*i];
  }
  #pragma unroll
  for (int i = 0; i < 2; ++i){
    int idx = 4*(t + 256*i);
    int col = idx >> 5;
    int dst = (idx & ~31) | ((idx & 31) ^ ((col & 7) << 2));
    *(uint4*)&sMTh[dst] = ((const uint4*)MThP)[t + 256*i];
    *(uint4*)&sMTl[dst] = ((const uint4*)MTlP)[t + 256*i];
  }
  __syncthreads();

  f32x4 acc[4];
  #pragma unroll
  for (int nt = 0; nt < 4; ++nt){
    float bdc = bd[nt*16 + colA];
    acc[nt] = (f32x4){bdc, bdc, bdc, bdc};
  }
  #pragma unroll
  for (int s = 0; s < 8; ++s){
    bf16x8 Ah, Al;
    mk_frags(xv[2*s], xv[2*s+1], Ah, Al);
    #pragma unroll
    for (int nt = 0; nt < 4; ++nt){
      int col = nt*16 + colA;
      int kw = s*16 + g*4;
      bf16x8 B = ld_frag(&sWdT[col*128 + (kw ^ ((col & 7) << 2))]);
      acc[nt] = __builtin_amdgcn_mfma_f32_16x16x32_bf16(Ah, B, acc[nt], 0, 0, 0);
      acc[nt] = __builtin_amdgcn_mfma_f32_16x16x32_bf16(Al, B, acc[nt], 0, 0, 0);
    }
  }
  #pragma unroll
  for (int nt = 0; nt < 4; ++nt){
    #pragma unroll
    for (int q = 0; q < 4; ++q)
      sNf[w][g*4 + q][nt*16 + colA] = fmaxf(acc[nt][q], 0.0f);
  }

  {
    const float* nr = &sNf[w][colA][g*16];
    float b = 0.0f;
    #pragma unroll
    for (int c = 0; c < 16; ++c) b = fmaf(nr[c], u[g*16 + c], b);
    b += __shfl_xor(b, 16);
    b += __shfl_xor(b, 32);
    int qrow = row0 + colA;
    if (lane < 16 && qrow < NN) qb[qrow] = b + s0p[0];
  }

  f32x4 acc2[4];
  #pragma unroll
  for (int nt = 0; nt < 4; ++nt){
    float cvl = cvec[nt*16 + colA];
    acc2[nt] = (f32x4){cvl, cvl, cvl, cvl};
  }
  #pragma unroll
  for (int s = 0; s < 2; ++s){
    const float* ar = &sNf[w][colA][s*32 + g*8];
    float4 e0 = *(const float4*)(ar);
    float4 e1 = *(const float4*)(ar + 4);
    bf16x8 Ah, Al;
    mk_frags(e0, e1, Ah, Al);
    #pragma unroll
    for (int nt = 0; nt < 4; ++nt){
      int col = nt*16 + colA;
      int kw = s*16 + g*4;
      bf16x8 Bh = ld_frag(&sMTh[col*32 + (kw ^ ((col & 7) << 2))]);
      bf16x8 Bl = ld_frag(&sMTl[col*32 + (kw ^ ((col & 7) << 2))]);
      acc2[nt] = __builtin_amdgcn_mfma_f32_16x16x32_bf16(Ah, Bh, acc2[nt], 0, 0, 0);
      acc2[nt] = __builtin_amdgcn_mfma_f32_16x16x32_bf16(Al, Bh, acc2[nt], 0, 0, 0);
      acc2[nt] = __builtin_amdgcn_mfma_f32_16x16x32_bf16(Ah, Bl, acc2[nt], 0, 0, 0);
    }
  }
  #pragma unroll
  for (int nt = 0; nt < 4; ++nt){
    #pragma unroll
    for (int q = 0; q < 4; ++q){
      int r = row0 + g*4 + q;
      if (r < NN) qkH[(size_t)r * D + nt*16 + colA] = f2b(acc2[nt][q]);
    }
  }
}

// ---------------- P3: EDGE-ORDER per-edge tf, cluster, attn ----------------
// v5: two edges INTERLEAVED in one d4-loop (round-8 counters showed VGPR=32:
// the compiler serialized the old sequential form and re-loaded qkH mid-loop).
// qkH loaded lazily as uint2/iter (2 L1 lines/edge); launch_bounds(256,4)
// grants ~128 VGPR so both edges' state stays live. Per-edge FMA sequence is
// bit-identical to the round-4 version -> attn/cl bits unchanged.
__global__ __launch_bounds__(256, 4) void p3_edge(
    const float* __restrict__ ea, const int* __restrict__ eidx,
    const float* __restrict__ Wt, const float* __restrict__ bt, const float* __restrict__ ce,
    const unsigned short* __restrict__ qkH, const float* __restrict__ qb,
    float* __restrict__ attnE, unsigned char* __restrict__ clE,
    unsigned* __restrict__ epc)
{
  __shared__ unsigned s_epc[NC];
  int t = threadIdx.x;
  if (t < NC) s_epc[t] = 0u;
  __syncthreads();
  int e0 = blockIdx.x * 512 + t;
  int e1 = e0 + 256;
  bool v1 = (e1 < EE);
  int e1c = v1 ? e1 : e0;
  int sA = eidx[e0];
  int sB = eidx[e1c];
  const float4* pa = (const float4*)(ea + (size_t)e0 * ED);
  const float4* pb = (const float4*)(ea + (size_t)e1c * ED);
  float4 A0 = pa[0], A1 = pa[1], A2 = pa[2], A3 = pa[3];
  float4 B0 = pb[0], B1 = pb[1], B2 = pb[2], B3 = pb[3];
  float qb0 = qb[sA];
  float qb1 = qb[sB];
  const uint2* qrA = (const uint2*)(qkH + (size_t)sA * D);
  const uint2* qrB = (const uint2*)(qkH + (size_t)sB * D);
  const float4* Wt4 = (const float4*)Wt;   // wave-uniform -> scalar path
  const float4* bt4 = (const float4*)bt;
  const float4* ce4 = (const float4*)ce;

  float eavA[ED] = {A0.x,A0.y,A0.z,A0.w, A1.x,A1.y,A1.z,A1.w,
                    A2.x,A2.y,A2.z,A2.w, A3.x,A3.y,A3.z,A3.w};
  float eavB[ED] = {B0.x,B0.y,B0.z,B0.w, B1.x,B1.y,B1.z,B1.w,
                    B2.x,B2.y,B2.z,B2.w, B3.x,B3.y,B3.z,B3.w};
  float simsA[NC], simsB[NC];
  #pragma unroll
  for (int c = 0; c < NC; ++c){ simsA[c] = 0.0f; simsB[c] = 0.0f; }
  float atA = qb0, atB = qb1;
  #pragma unroll
  for (int d4 = 0; d4 < D/4; ++d4){
    uint2 qa  = qrA[d4];   // words 2*d4, 2*d4+1 (same values/order as v4)
    uint2 qbw = qrB[d4];
    float4 bv = bt4[d4];
    float4 accA = bv, accB = bv;
    #pragma unroll
    for (int j = 0; j < ED; ++j){
      float4 wv = Wt4[j*(D/4) + d4];
      accA.x = fmaf(eavA[j], wv.x, accA.x);
      accA.y = fmaf(eavA[j], wv.y, accA.y);
      accA.z = fmaf(eavA[j], wv.z, accA.z);
      accA.w = fmaf(eavA[j], wv.w, accA.w);
      accB.x = fmaf(eavB[j], wv.x, accB.x);
      accB.y = fmaf(eavB[j], wv.y, accB.y);
      accB.z = fmaf(eavB[j], wv.z, accB.z);
      accB.w = fmaf(eavB[j], wv.w, accB.w);
    }
    float tA0 = fmaxf(accA.x, 0.0f), tA1 = fmaxf(accA.y, 0.0f);
    float tA2 = fmaxf(accA.z, 0.0f), tA3 = fmaxf(accA.w, 0.0f);
    float tB0 = fmaxf(accB.x, 0.0f), tB1 = fmaxf(accB.y, 0.0f);
    float tB2 = fmaxf(accB.z, 0.0f), tB3 = fmaxf(accB.w, 0.0f);
    #pragma unroll
    for (int c = 0; c < NC; ++c){
      float4 cv = ce4[c*(D/4) + d4];
      simsA[c] = fmaf(tA0, cv.x, simsA[c]);
      simsA[c] = fmaf(tA1, cv.y, simsA[c]);
      simsA[c] = fmaf(tA2, cv.z, simsA[c]);
      simsA[c] = fmaf(tA3, cv.w, simsA[c]);
      simsB[c] = fmaf(tB0, cv.x, simsB[c]);
      simsB[c] = fmaf(tB1, cv.y, simsB[c]);
      simsB[c] = fmaf(tB2, cv.z, simsB[c]);
      simsB[c] = fmaf(tB3, cv.w, simsB[c]);
    }
    atA = fmaf(blo(qa.x),  tA0, atA);
    atA = fmaf(bhi(qa.x),  tA1, atA);
    atA = fmaf(blo(qa.y),  tA2, atA);
    atA = fmaf(bhi(qa.y),  tA3, atA);
    atB = fmaf(blo(qbw.x), tB0, atB);
    atB = fmaf(bhi(qbw.x), tB1, atB);
    atB = fmaf(blo(qbw.y), tB2, atB);
    atB = fmaf(bhi(qbw.y), tB3, atB);
  }
  {
    float best = NEGINF; int bc = 0;
    #pragma unroll
    for (int c = 0; c < NC; ++c){
      if (simsA[c] > best){ best = simsA[c]; bc = c; }
    }
    attnE[e0] = atA * 0.125f;
    clE[e0] = (unsigned char)bc;
    atomicAdd(&s_epc[bc], 1u);
  }
  if (v1){
    float best = NEGINF; int bc = 0;
    #pragma unroll
    for (int c = 0; c < NC; ++c){
      if (simsB[c] > best){ best = simsB[c]; bc = c; }
    }
    attnE[e1] = atB * 0.125f;
    clE[e1] = (unsigned char)bc;
    atomicAdd(&s_epc[bc], 1u);
  }
  __syncthreads();
  if (t < NC){
    unsigned v = s_epc[t];
    if (v) atomicAdd(&epc[t], v);
  }
}

// ---------------- P4: per-node softmax + T accumulation (wave per node) -----
// round-4 proven version: pass A (LDS atomics over pairS gather) + scalar
// pass B. [Round-8 lesson: LDS-block atomics are ~free; scattered global
// atomics cost ~25-30 ns each -- do NOT fuse den/cnt into p3.]
#define EROW 20   // padded LDS row stride (floats) for ea staging
__global__ __launch_bounds__(256) void p4_node(
    const float* __restrict__ ea, const int2* __restrict__ pairS,
    const float* __restrict__ Wt, const float* __restrict__ bt,
    const float* __restrict__ attnE, const unsigned char* __restrict__ clE,
    const int* __restrict__ rowptr,
    float* __restrict__ T, float* __restrict__ S)
{
  __shared__ float s_den[4][NC];
  __shared__ int   s_cnt[4][NC];
  __shared__ float s_inv[4][NC];
  __shared__ float s_coef[4][64];
  __shared__ float s_ea[4][64][EROW];   // 20 KB
  int t = threadIdx.x, lane = t & 63, w = t >> 6;
  float wl[ED];
  #pragma unroll
  for (int j = 0; j < ED; ++j) wl[j] = Wt[j*D + lane];
  float btl = bt[lane];
  if (lane < NC){ s_den[w][lane] = 0.0f; s_cnt[w][lane] = 0; }
  int node = blockIdx.x * 4 + w;
  int start = rowptr[node], end = rowptr[node + 1];
  for (int base = start; base < end; base += 64){
    int idx = base + lane;
    if (idx < end){
      int e = pairS[idx].x;
      float ex = __expf(attnE[e]);
      int c = clE[e];
      atomicAdd(&s_den[w][c], ex);
      atomicAdd(&s_cnt[w][c], 1);
    }
  }
  if (lane < NC){
    int   cc = s_cnt[w][lane];
    float dd = s_den[w][lane];
    s_inv[w][lane] = (cc > 0) ? 1.0f / (dd * (float)cc) : 0.0f;
    float sv = (cc > 0) ? 1.0f / (float)cc : 0.0f;
    sv += __shfl_xor(sv, 1); sv += __shfl_xor(sv, 2); sv += __shfl_xor(sv, 4);
    if (lane == 0) S[node] = sv;
  }
  float Tacc = 0.0f;
  for (int base = start; base < end; base += 64){
    int idx = base + lane;
    if (idx < end){
      int e = pairS[idx].x;
      s_coef[w][lane] = __expf(attnE[e]) * s_inv[w][clE[e]];
    }
    #pragma unroll
    for (int r = 0; r < 4; ++r){
      int slot = base + r*16 + (lane >> 2);
      if (slot < end){
        int e = pairS[slot].x;
        float4 v = ((const float4*)ea)[(size_t)e*4 + (lane & 3)];
        *(float4*)&s_ea[w][slot - base][(lane & 3)*4] = v;
      }
    }
    int mm = min(64, end - base);
    for (int tt = 0; tt < mm; ++tt){
      float coef = s_coef[w][tt];
      const float4* er = (const float4*)&s_ea[w][tt][0];
      float4 e0 = er[0], e1 = er[1], e2 = er[2], e3 = er[3];
      float tfv = btl;
      tfv = fmaf(e0.x, wl[0], tfv);  tfv = fmaf(e0.y, wl[1], tfv);
      tfv = fmaf(e0.z, wl[2], tfv);  tfv = fmaf(e0.w, wl[3], tfv);
      tfv = fmaf(e1.x, wl[4], tfv);  tfv = fmaf(e1.y, wl[5], tfv);
      tfv = fmaf(e1.z, wl[6], tfv);  tfv = fmaf(e1.w, wl[7], tfv);
      tfv = fmaf(e2.x, wl[8], tfv);  tfv = fmaf(e2.y, wl[9], tfv);
      tfv = fmaf(e2.z, wl[10], tfv); tfv = fmaf(e2.w, wl[11], tfv);
      tfv = fmaf(e3.x, wl[12], tfv); tfv = fmaf(e3.y, wl[13], tfv);
      tfv = fmaf(e3.z, wl[14], tfv); tfv = fmaf(e3.w, wl[15], tfv);
      tfv = fmaxf(tfv, 0.0f);
      Tacc = fmaf(coef, tfv, Tacc);
    }
  }
  T[(size_t)node * D + lane] = Tacc;
}

// ---------------- K5: fu = relu((T@Wvo + S*bvo)/nne + bo); out = x + fu@Wu+bu
__global__ __launch_bounds__(256) void k5_out(
    const float* __restrict__ x, const float* __restrict__ T, const float* __restrict__ S,
    const float* __restrict__ Wvo, const float* __restrict__ bvo,
    const unsigned* __restrict__ WuP, const float* __restrict__ bu,
    const float* __restrict__ bo, const unsigned* __restrict__ epc,
    float* __restrict__ out)
{
  __shared__ unsigned sWuP[8192];   // 32 KB packed bf16 Wu
  __shared__ float s_fu[16*64];     // 4 KB
  int t = threadIdx.x;
  #pragma unroll
  for (int i = 0; i < 8; ++i)
    ((uint4*)sWuP)[t + 256*i] = ((const uint4*)WuP)[t + 256*i];
  int lane = t & 63;
  int wg = __builtin_amdgcn_readfirstlane(t >> 6);
  int n0 = blockIdx.x * 16 + wg * 4;
  float nne = 0.0f;
  #pragma unroll
  for (int c = 0; c < NC; ++c) nne += (epc[c] > 0u) ? 1.0f : 0.0f;
  float inv = 1.0f / fmaxf(nne, 1.0f);
  float T0 = T[(size_t)(n0+0)*D + lane];
  float T1 = T[(size_t)(n0+1)*D + lane];
  float T2 = T[(size_t)(n0+2)*D + lane];
  float T3 = T[(size_t)(n0+3)*D + lane];
  float bvl = bvo[lane], bol = bo[lane];
  float f0 = S[n0+0]*bvl, f1 = S[n0+1]*bvl, f2 = S[n0+2]*bvl, f3 = S[n0+3]*bvl;
  #pragma unroll 8
  for (int i = 0; i < 64; ++i){
    float wv = Wvo[i*64 + lane];
    f0 = fmaf(__shfl(T0, i), wv, f0);
    f1 = fmaf(__shfl(T1, i), wv, f1);
    f2 = fmaf(__shfl(T2, i), wv, f2);
    f3 = fmaf(__shfl(T3, i), wv, f3);
  }
  f0 = fmaxf(f0*inv + bol, 0.0f);
  f1 = fmaxf(f1*inv + bol, 0.0f);
  f2 = fmaxf(f2*inv + bol, 0.0f);
  f3 = fmaxf(f3*inv + bol, 0.0f);
  s_fu[(wg*4+0)*64 + lane] = f0;
  s_fu[(wg*4+1)*64 + lane] = f1;
  s_fu[(wg*4+2)*64 + lane] = f2;
  s_fu[(wg*4+3)*64 + lane] = f3;
  __syncthreads();
  float4 bu4 = ((const float4*)bu)[lane];
  float4 o0 = ((const float4*)(x + (size_t)(n0+0)*INCH))[lane];
  float4 o1 = ((const float4*)(x + (size_t)(n0+1)*INCH))[lane];
  float4 o2 = ((const float4*)(x + (size_t)(n0+2)*INCH))[lane];
  float4 o3 = ((const float4*)(x + (size_t)(n0+3)*INCH))[lane];
  o0.x += bu4.x; o0.y += bu4.y; o0.z += bu4.z; o0.w += bu4.w;
  o1.x += bu4.x; o1.y += bu4.y; o1.z += bu4.z; o1.w += bu4.w;
  o2.x += bu4.x; o2.y += bu4.y; o2.z += bu4.z; o2.w += bu4.w;
  o3.x += bu4.x; o3.y += bu4.y; o3.z += bu4.z; o3.w += bu4.w;
  const float2* fu2 = (const float2*)s_fu;
  #pragma unroll 4
  for (int d2 = 0; d2 < 32; ++d2){
    uint4 wp = *(const uint4*)&sWuP[d2*256 + lane*4];
    float4 wlv = { blo(wp.x), blo(wp.y), blo(wp.z), blo(wp.w) };
    float4 wh  = { bhi(wp.x), bhi(wp.y), bhi(wp.z), bhi(wp.w) };
    float2 g0 = fu2[(wg*4+0)*32 + d2];
    float2 g1 = fu2[(wg*4+1)*32 + d2];
    float2 g2 = fu2[(wg*4+2)*32 + d2];
    float2 g3 = fu2[(wg*4+3)*32 + d2];
    o0.x = fmaf(g0.x, wlv.x, o0.x); o0.y = fmaf(g0.x, wlv.y, o0.y);
    o0.z = fmaf(g0.x, wlv.z, o0.z); o0.w = fmaf(g0.x, wlv.w, o0.w);
    o0.x = fmaf(g0.y, wh.x, o0.x);  o0.y = fmaf(g0.y, wh.y, o0.y);
    o0.z = fmaf(g0.y, wh.z, o0.z);  o0.w = fmaf(g0.y, wh.w, o0.w);
    o1.x = fmaf(g1.x, wlv.x, o1.x); o1.y = fmaf(g1.x, wlv.y, o1.y);
    o1.z = fmaf(g1.x, wlv.z, o1.z); o1.w = fmaf(g1.x, wlv.w, o1.w);
    o1.x = fmaf(g1.y, wh.x, o1.x);  o1.y = fmaf(g1.y, wh.y, o1.y);
    o1.z = fmaf(g1.y, wh.z, o1.z);  o1.w = fmaf(g1.y, wh.w, o1.w);
    o2.x = fmaf(g2.x, wlv.x, o2.x); o2.y = fmaf(g2.x, wlv.y, o2.y);
    o2.z = fmaf(g2.x, wlv.z, o2.z); o2.w = fmaf(g2.x, wlv.w, o2.w);
    o2.x = fmaf(g2.y, wh.x, o2.x);  o2.y = fmaf(g2.y, wh.y, o2.y);
    o2.z = fmaf(g2.y, wh.z, o2.z);  o2.w = fmaf(g2.y, wh.w, o2.w);
    o3.x = fmaf(g3.x, wlv.x, o3.x); o3.y = fmaf(g3.x, wlv.y, o3.y);
    o3.z = fmaf(g3.x, wlv.z, o3.z); o3.w = fmaf(g3.x, wlv.w, o3.w);
    o3.x = fmaf(g3.y, wh.x, o3.x);  o3.y = fmaf(g3.y, wh.y, o3.y);
    o3.z = fmaf(g3.y, wh.z, o3.z);  o3.w = fmaf(g3.y, wh.w, o3.w);
  }
  ((float4*)(out + (size_t)(n0+0)*INCH))[lane] = o0;
  ((float4*)(out + (size_t)(n0+1)*INCH))[lane] = o1;
  ((float4*)(out + (size_t)(n0+2)*INCH))[lane] = o2;
  ((float4*)(out + (size_t)(n0+3)*INCH))[lane] = o3;
}

extern "C" void kernel_launch(void* const* d_in, const int* in_sizes, int n_in,
                              void* d_out, int out_size, void* d_ws, size_t ws_size,
                              hipStream_t stream)
{
  const float* x  = (const float*)d_in[0];
  const float* ea = (const float*)d_in[1];
  const int* eidx = (const int*)d_in[2];      // [2,E]; row 0 = src
  const float* Wd = (const float*)d_in[3];  const float* bd = (const float*)d_in[4];
  const float* Wu = (const float*)d_in[5];  const float* bu = (const float*)d_in[6];
  const float* Wt = (const float*)d_in[7];  const float* bt = (const float*)d_in[8];
  const float* Wq = (const float*)d_in[9];  const float* bq = (const float*)d_in[10];
  const float* Wk = (const float*)d_in[11]; const float* bk = (const float*)d_in[12];
  const float* Wv = (const float*)d_in[13]; const float* bv = (const float*)d_in[14];
  const float* ce = (const float*)d_in[15];
  const float* Wo = (const float*)d_in[16]; const float* bo = (const float*)d_in[17];
  float* out = (float*)d_out;

  size_t need = 0;
  need += (size_t)NN*4;          // cnt
  need += (size_t)NN*4;          // fill
  need += 64;                    // epc
  size_t zbytes = need;          // zero region
  need += (size_t)(NN+4)*4;      // rowptr
  need += 1024;                  // bsum
  need += (size_t)NN*D*2;        // qkH (bf16)
  need += (size_t)NN*4;          // qb
  need += (size_t)EE*8;          // pairS
  need += (size_t)EE*4;          // attnE
  need += (size_t)EE;            // clE
  need += 16;                    // align
  need += (size_t)NN*D*4;        // T
  need += (size_t)NN*4;          // S
  need += 256 + 256 + 16 + 4096*4 + 256;   // cvec,u,s0,Wvo,bvo
  need += 8192*4 + 8192*4;       // WdTP, WuP
  need += 2048*4 + 2048*4;       // MThP, MTlP
  need += 1024*4 + 1024*4;       // WtTPh, WtTPl

  char* w = (char*)d_ws;
  if (ws_size < need){
    void* p = nullptr;
    hipGetSymbolAddress(&p, HIP_SYMBOL(g_ws));
    w = (char*)p;
  }
  size_t off = 0;
  int*      cnt    = (int*)(w + off);      off += (size_t)NN*4;
  int*      fill   = (int*)(w + off);      off += (size_t)NN*4;
  unsigned* epc    = (unsigned*)(w + off); off += 64;
  int*      rowptr = (int*)(w + off);      off += (size_t)(NN+4)*4;
  int*      bsum   = (int*)(w + off);      off += 1024;
  unsigned short* qkH = (unsigned short*)(w + off); off += (size_t)NN*D*2;
  float*    qb     = (float*)(w + off);    off += (size_t)NN*4;
  int2*     pairS  = (int2*)(w + off);     off += (size_t)EE*8;
  float*    attnE  = (float*)(w + off);    off += (size_t)EE*4;
  unsigned char* clE = (unsigned char*)(w + off); off += (size_t)EE;
  off = (off + 15) & ~(size_t)15;
  float*    T      = (float*)(w + off);    off += (size_t)NN*D*4;
  float*    S      = (float*)(w + off);    off += (size_t)NN*4;
  float*    cvec   = (float*)(w + off);    off += 256;
  float*    u      = (float*)(w + off);    off += 256;
  float*    s0     = (float*)(w + off);    off += 16;
  float*    Wvo    = (float*)(w + off);    off += 4096*4;
  float*    bvo    = (float*)(w + off);    off += 256;
  unsigned* WdTP   = (unsigned*)(w + off); off += 8192*4;
  unsigned* WuP    = (unsigned*)(w + off); off += 8192*4;
  unsigned* MThP   = (unsigned*)(w + off); off += 2048*4;
  unsigned* MTlP   = (unsigned*)(w + off); off += 2048*4;
  unsigned* WtTPh  = (unsigned*)(w + off); off += 1024*4;
  unsigned* WtTPl  = (unsigned*)(w + off); off += 1024*4;

  int zwords = (int)(zbytes / 4);
  Adapter_30872224923942_kernel<<<dim3(128), dim3(256), 0, stream>>>((unsigned*)w, zwords);
  kpre<<<dim3(28), dim3(256), 0, stream>>>(Wq, bq, Wk, bk, Wv, bv, Wo, Wd, Wu, Wt,
                                           cvec, u, s0, Wvo, bvo, WdTP, WuP,
                                           MThP, MTlP, WtTPh, WtTPl);
  p1_hist<<<dim3(EE/256), dim3(256), 0, stream>>>(eidx, cnt);
  s1_scan<<<dim3(NB), dim3(256), 0, stream>>>(cnt, rowptr, bsum);
  s2_scan<<<dim3(1),  dim3(256), 0, stream>>>(bsum);
  s3_add <<<dim3(NB), dim3(256), 0, stream>>>(rowptr, bsum);
  p2_build<<<dim3(EE/256), dim3(256), 0, stream>>>(eidx, rowptr, fill, pairS);
  k1_node<<<dim3((NN + 63)/64), dim3(256), 0, stream>>>(x, WdTP, bd, MThP, MTlP,
                                                        cvec, u, s0, qkH, qb);
  p3_edge<<<dim3((EE + 511)/512), dim3(256), 0, stream>>>(ea, eidx, Wt, bt, ce, qkH, qb,
                                                          attnE, clE, epc);
  p4_node<<<dim3(NN/4), dim3(256), 0, stream>>>(ea, pairS, Wt, bt, attnE, clE, rowptr, T, S);
  k5_out <<<dim3(NN/16), dim3(256), 0, stream>>>(x, T, S, Wvo, bvo, WuP, bu, bo, epc, out);
}

// Round 10
// 417.619 us; speedup vs baseline: 1.3056x; 1.3056x over previous
//
#include <hip/hip_runtime.h>

#define NN 50000
#define EE 800000
#define INCH 256
#define D 64
#define ED 16
#define NC 8
#define NB 196          // scan blocks: 196*256 = 50176 >= NN
#define NEGINF (-3.0e38f)

// fallback scratch (need ~32 MB)
__device__ __align__(16) char g_ws[64u << 20];

typedef __attribute__((ext_vector_type(8))) short bf16x8;
typedef __attribute__((ext_vector_type(4))) float f32x4;

__device__ __forceinline__ unsigned short f2b(float f){
  unsigned u = __float_as_uint(f);
  return (unsigned short)((u + 0x7fffu + ((u >> 16) & 1u)) >> 16);
}
__device__ __forceinline__ unsigned packbf(float lo, float hi){
  return (unsigned)f2b(lo) | ((unsigned)f2b(hi) << 16);
}
__device__ __forceinline__ float blo(unsigned w){ return __uint_as_float(w << 16); }
__device__ __forceinline__ float bhi(unsigned w){ return __uint_as_float(w & 0xffff0000u); }

union FragU { unsigned u[4]; uint4 q; bf16x8 b; };
__device__ __forceinline__ bf16x8 as_frag(unsigned a, unsigned b, unsigned c, unsigned d){
  FragU t; t.u[0]=a; t.u[1]=b; t.u[2]=c; t.u[3]=d; return t.b;
}
__device__ __forceinline__ bf16x8 ld_frag(const unsigned* p){
  FragU t; t.q = *(const uint4*)p; return t.b;
}
// split a,b into bf16 hi-word + bf16 lo(residual)-word
__device__ __forceinline__ void split2(float a, float b, unsigned &hi, unsigned &lo){
  hi = packbf(a, b);
  lo = packbf(a - blo(hi), b - bhi(hi));
}
__device__ __forceinline__ void mk_frags(float4 e0, float4 e1, bf16x8 &Ah, bf16x8 &Al){
  unsigned h0,h1,h2,h3,l0,l1,l2,l3;
  split2(e0.x, e0.y, h0, l0);
  split2(e0.z, e0.w, h1, l1);
  split2(e1.x, e1.y, h2, l2);
  split2(e1.z, e1.w, h3, l3);
  Ah = as_frag(h0,h1,h2,h3);
  Al = as_frag(l0,l1,l2,l3);
}

// ---------------- K0: zero cnt/fill/epc (harness-named kernel) --------------
__global__ __launch_bounds__(256) void Adapter_30872224923942_kernel(
    unsigned* __restrict__ ws, int nwords)
{
  int stride = gridDim.x * 256;
  for (int i = blockIdx.x * 256 + threadIdx.x; i < nwords; i += stride)
    ws[i] = 0u;
}

// ---------------- kpre: weight folds + bf16 packs ---------------------------
__global__ __launch_bounds__(256) void kpre(
    const float* __restrict__ Wq, const float* __restrict__ bq,
    const float* __restrict__ Wk, const float* __restrict__ bk,
    const float* __restrict__ Wv, const float* __restrict__ bv,
    const float* __restrict__ Wo, const float* __restrict__ Wd,
    const float* __restrict__ Wu, const float* __restrict__ Wt,
    float* __restrict__ cvec, float* __restrict__ u,
    float* __restrict__ s0, float* __restrict__ Wvo, float* __restrict__ bvo,
    unsigned* __restrict__ WdTP, unsigned* __restrict__ WuP,
    unsigned* __restrict__ MThP, unsigned* __restrict__ MTlP,
    unsigned* __restrict__ WtTPh, unsigned* __restrict__ WtTPl)
{
  int b = blockIdx.x, t = threadIdx.x;
  if (b < 16){
    int i = b*4 + (t >> 6), j = t & 63;
    float acc = 0.0f;
    for (int d = 0; d < D; ++d) acc = fmaf(Wv[i*D+d], Wo[d*D+j], acc);
    Wvo[i*D+j] = acc;
  } else if (b < 20){
    // WdTP[col*128 + kw] = (Wd[2kw][col], Wd[2kw+1][col])
    for (int k = 0; k < 8; ++k){
      int idx = (b-16)*2048 + t*8 + k;
      int col = idx >> 7, kw = idx & 127;
      WdTP[idx] = packbf(Wd[(2*kw)*D + col], Wd[(2*kw+1)*D + col]);
    }
  } else if (b < 24){
    for (int k = 0; k < 8; ++k){
      int idx = (b-20)*2048 + t*8 + k;
      int d2 = idx >> 8, c = idx & 255;
      WuP[idx] = packbf(Wu[(2*d2)*INCH + c], Wu[(2*d2+1)*INCH + c]);
    }
  } else if (b < 26){
    // M[i][j] = Wq[i]·Wk[j]; MT packed along k at fixed col j, split hi/lo
    for (int k = 0; k < 4; ++k){
      int idx = (b-24)*1024 + t*4 + k;
      int j = idx >> 5, kw = idx & 31;
      float m0 = 0.0f, m1 = 0.0f;
      for (int d = 0; d < D; ++d) m0 = fmaf(Wq[(2*kw  )*D+d], Wk[j*D+d], m0);
      for (int d = 0; d < D; ++d) m1 = fmaf(Wq[(2*kw+1)*D+d], Wk[j*D+d], m1);
      unsigned hi = packbf(m0, m1);
      MThP[idx] = hi;
      MTlP[idx] = packbf(m0 - blo(hi), m1 - bhi(hi));
    }
  } else if (b < 27){
    // WtTP[col*16 + kw] (unused by current p4; kept for layout stability)
    for (int k = 0; k < 4; ++k){
      int idx = t*4 + k;               // 1024 entries
      int col = idx >> 4, kw = idx & 15;
      unsigned hi = 0u, lo = 0u;
      if (kw < 8) split2(Wt[(2*kw)*D + col], Wt[(2*kw+1)*D + col], hi, lo);
      WtTPh[idx] = hi;
      WtTPl[idx] = lo;
    }
  } else {
    if (t < 64){
      float acc = 0.0f;
      for (int d = 0; d < D; ++d) acc = fmaf(Wk[t*D+d], bq[d], acc);
      cvec[t] = acc;
    } else if (t < 128){
      int i = t - 64; float acc = 0.0f;
      for (int d = 0; d < D; ++d) acc = fmaf(Wq[i*D+d], bk[d], acc);
      u[i] = acc;
    } else if (t < 192){
      int j = t - 128; float acc = 0.0f;
      for (int d = 0; d < D; ++d) acc = fmaf(bv[d], Wo[d*D+j], acc);
      bvo[j] = acc;
    } else if (t == 192){
      float acc = 0.0f;
      for (int d = 0; d < D; ++d) acc = fmaf(bq[d], bk[d], acc);
      s0[0] = acc;
    }
  }
}

// ---------------- P1: histogram of src --------------------------------------
__global__ __launch_bounds__(256) void p1_hist(
    const int* __restrict__ eidx, int* __restrict__ cnt)
{
  int e = blockIdx.x * 256 + threadIdx.x;
  if (e < EE) atomicAdd(&cnt[eidx[e]], 1);
}

// ---------------- S1..S3: exclusive scan ------------------------------------
__global__ __launch_bounds__(256) void s1_scan(
    const int* __restrict__ cnt, int* __restrict__ rowptr, int* __restrict__ bsum)
{
  __shared__ int s[256];
  int t = threadIdx.x;
  int i = blockIdx.x * 256 + t;
  int v = (i < NN) ? cnt[i] : 0;
  s[t] = v; __syncthreads();
  #pragma unroll
  for (int off = 1; off < 256; off <<= 1){
    int add = (t >= off) ? s[t - off] : 0;
    __syncthreads();
    s[t] += add;
    __syncthreads();
  }
  if (i < NN) rowptr[i] = s[t] - v;
  if (t == 255) bsum[blockIdx.x] = s[255];
}
__global__ __launch_bounds__(256) void s2_scan(int* __restrict__ bsum)
{
  __shared__ int s[256];
  int t = threadIdx.x;
  int v = (t < NB) ? bsum[t] : 0;
  s[t] = v; __syncthreads();
  #pragma unroll
  for (int off = 1; off < 256; off <<= 1){
    int add = (t >= off) ? s[t - off] : 0;
    __syncthreads();
    s[t] += add;
    __syncthreads();
  }
  if (t < NB) bsum[t] = s[t] - v;
}
__global__ __launch_bounds__(256) void s3_add(
    int* __restrict__ rowptr, const int* __restrict__ bsum)
{
  int i = blockIdx.x * 256 + threadIdx.x;
  if (i < NN) rowptr[i] += bsum[blockIdx.x];
  if (i == 0) rowptr[NN] = EE;
}

// ---------------- P2: build CSR pair list (the one amplified scatter) -------
__global__ __launch_bounds__(256) void p2_build(
    const int* __restrict__ eidx, const int* __restrict__ rowptr,
    int* __restrict__ fill, int2* __restrict__ pairS)
{
  int e = blockIdx.x * 256 + threadIdx.x;
  if (e >= EE) return;
  int src = eidx[e];
  int r = atomicAdd(&fill[src], 1);
  int2 pr; pr.x = e; pr.y = src;
  pairS[rowptr[src] + r] = pr;
}

// ---------------- K1: nf = relu(x@Wd+bd) -> qkH = bf16(nf@M+cvec), qb -------
// v3 (validated round 4): MFMA with split-bf16 on both operands.
__global__ __launch_bounds__(256) void k1_node(
    const float* __restrict__ x, const unsigned* __restrict__ WdTP,
    const float* __restrict__ bd,
    const unsigned* __restrict__ MThP, const unsigned* __restrict__ MTlP,
    const float* __restrict__ cvec, const float* __restrict__ u,
    const float* __restrict__ s0p,
    unsigned short* __restrict__ qkH, float* __restrict__ qb)
{
  __shared__ unsigned sWdT[8192];     // 32 KB [64 col][128 kw], xor-swizzled
  __shared__ unsigned sMTh[2048];     // 8 KB [64 col][32 kw], xor-swizzled
  __shared__ unsigned sMTl[2048];     // 8 KB
  __shared__ float sNf[4][16][68];    // 17 KB nf tile
  int t = threadIdx.x;
  int lane = t & 63;
  int w = t >> 6;
  int colA = lane & 15;               // A row / C col within tile
  int g = lane >> 4;                  // k-group
  int row0 = blockIdx.x * 64 + w * 16;

  int arow = row0 + colA;
  const float* xp = x + (size_t)min(arow, NN-1) * INCH + (g << 3);
  float4 xv[16];
  #pragma unroll
  for (int s = 0; s < 8; ++s){
    xv[2*s  ] = ((const float4*)(xp + s*32))[0];
    xv[2*s+1] = ((const float4*)(xp + s*32))[1];
  }
  #pragma unroll
  for (int i = 0; i < 8; ++i){
    int idx = 4*(t + 256*i);
    int col = idx >> 7;
    int dst = (idx & ~127) | ((idx & 127) ^ ((col & 7) << 2));
    *(uint4*)&sWdT[dst] = ((const uint4*)WdTP)[t + 256*i];
  }
  #pragma unroll
  for (int i = 0; i < 2; ++i){
    int idx = 4*(t + 256*i);
    int col = idx >> 5;
    int dst = (idx & ~31) | ((idx & 31) ^ ((col & 7) << 2));
    *(uint4*)&sMTh[dst] = ((const uint4*)MThP)[t + 256*i];
    *(uint4*)&sMTl[dst] = ((const uint4*)MTlP)[t + 256*i];
  }
  __syncthreads();

  f32x4 acc[4];
  #pragma unroll
  for (int nt = 0; nt < 4; ++nt){
    float bdc = bd[nt*16 + colA];
    acc[nt] = (f32x4){bdc, bdc, bdc, bdc};
  }
  #pragma unroll
  for (int s = 0; s < 8; ++s){
    bf16x8 Ah, Al;
    mk_frags(xv[2*s], xv[2*s+1], Ah, Al);
    #pragma unroll
    for (int nt = 0; nt < 4; ++nt){
      int col = nt*16 + colA;
      int kw = s*16 + g*4;
      bf16x8 B = ld_frag(&sWdT[col*128 + (kw ^ ((col & 7) << 2))]);
      acc[nt] = __builtin_amdgcn_mfma_f32_16x16x32_bf16(Ah, B, acc[nt], 0, 0, 0);
      acc[nt] = __builtin_amdgcn_mfma_f32_16x16x32_bf16(Al, B, acc[nt], 0, 0, 0);
    }
  }
  #pragma unroll
  for (int nt = 0; nt < 4; ++nt){
    #pragma unroll
    for (int q = 0; q < 4; ++q)
      sNf[w][g*4 + q][nt*16 + colA] = fmaxf(acc[nt][q], 0.0f);
  }

  {
    const float* nr = &sNf[w][colA][g*16];
    float b = 0.0f;
    #pragma unroll
    for (int c = 0; c < 16; ++c) b = fmaf(nr[c], u[g*16 + c], b);
    b += __shfl_xor(b, 16);
    b += __shfl_xor(b, 32);
    int qrow = row0 + colA;
    if (lane < 16 && qrow < NN) qb[qrow] = b + s0p[0];
  }

  f32x4 acc2[4];
  #pragma unroll
  for (int nt = 0; nt < 4; ++nt){
    float cvl = cvec[nt*16 + colA];
    acc2[nt] = (f32x4){cvl, cvl, cvl, cvl};
  }
  #pragma unroll
  for (int s = 0; s < 2; ++s){
    const float* ar = &sNf[w][colA][s*32 + g*8];
    float4 e0 = *(const float4*)(ar);
    float4 e1 = *(const float4*)(ar + 4);
    bf16x8 Ah, Al;
    mk_frags(e0, e1, Ah, Al);
    #pragma unroll
    for (int nt = 0; nt < 4; ++nt){
      int col = nt*16 + colA;
      int kw = s*16 + g*4;
      bf16x8 Bh = ld_frag(&sMTh[col*32 + (kw ^ ((col & 7) << 2))]);
      bf16x8 Bl = ld_frag(&sMTl[col*32 + (kw ^ ((col & 7) << 2))]);
      acc2[nt] = __builtin_amdgcn_mfma_f32_16x16x32_bf16(Ah, Bh, acc2[nt], 0, 0, 0);
      acc2[nt] = __builtin_amdgcn_mfma_f32_16x16x32_bf16(Al, Bh, acc2[nt], 0, 0, 0);
      acc2[nt] = __builtin_amdgcn_mfma_f32_16x16x32_bf16(Ah, Bl, acc2[nt], 0, 0, 0);
    }
  }
  #pragma unroll
  for (int nt = 0; nt < 4; ++nt){
    #pragma unroll
    for (int q = 0; q < 4; ++q){
      int r = row0 + g*4 + q;
      if (r < NN) qkH[(size_t)r * D + nt*16 + colA] = f2b(acc2[nt][q]);
    }
  }
}

// ---------------- P3: EDGE-ORDER per-edge tf, cluster, attn ----------------
// round-4 proven version (64 us, VGPR 32, no spills). [Round-9 lesson: the
// interleaved variant needs ~110 live VGPR; launch_bounds caps but does not
// grant registers -> 67 MB scratch spill, 178 us. Do not restructure without
// checking predicted live-set vs allocator cap.]
__global__ __launch_bounds__(256) void p3_edge(
    const float* __restrict__ ea, const int* __restrict__ eidx,
    const float* __restrict__ Wt, const float* __restrict__ bt, const float* __restrict__ ce,
    const unsigned short* __restrict__ qkH, const float* __restrict__ qb,
    float* __restrict__ attnE, unsigned char* __restrict__ clE,
    unsigned* __restrict__ epc)
{
  __shared__ unsigned s_epc[NC];
  int t = threadIdx.x;
  if (t < NC) s_epc[t] = 0u;
  __syncthreads();
  int e0 = blockIdx.x * 512 + t;
  int e1 = e0 + 256;
  bool v1 = (e1 < EE);
  int e1c = v1 ? e1 : e0;
  int sA = eidx[e0];
  int sB = eidx[e1c];
  const float4* pa = (const float4*)(ea + (size_t)e0 * ED);
  float4 A0 = pa[0], A1 = pa[1], A2 = pa[2], A3 = pa[3];
  float qb0 = qb[sA];
  const float4* pb = (const float4*)(ea + (size_t)e1c * ED);
  float4 B0 = pb[0], B1 = pb[1], B2 = pb[2], B3 = pb[3];
  float qb1 = qb[sB];
  uint4 QA[8], QB[8];
  {
    const uint4* qp = (const uint4*)(qkH + (size_t)sA * D);
    #pragma unroll
    for (int i = 0; i < 8; ++i) QA[i] = qp[i];
  }
  {
    const uint4* qp = (const uint4*)(qkH + (size_t)sB * D);
    #pragma unroll
    for (int i = 0; i < 8; ++i) QB[i] = qp[i];
  }
  const float4* Wt4 = (const float4*)Wt;
  const float4* bt4 = (const float4*)bt;
  const float4* ce4 = (const float4*)ce;

  // ---- edge 0 ----
  {
    float eav[ED] = {A0.x,A0.y,A0.z,A0.w, A1.x,A1.y,A1.z,A1.w,
                     A2.x,A2.y,A2.z,A2.w, A3.x,A3.y,A3.z,A3.w};
    float sims[NC];
    #pragma unroll
    for (int c = 0; c < NC; ++c) sims[c] = 0.0f;
    float at = qb0;
    #pragma unroll
    for (int d4 = 0; d4 < D/4; ++d4){
      float4 acc = bt4[d4];
      #pragma unroll
      for (int j = 0; j < ED; ++j){
        float4 wv = Wt4[j*(D/4) + d4];
        acc.x = fmaf(eav[j], wv.x, acc.x);
        acc.y = fmaf(eav[j], wv.y, acc.y);
        acc.z = fmaf(eav[j], wv.z, acc.z);
        acc.w = fmaf(eav[j], wv.w, acc.w);
      }
      float t0 = fmaxf(acc.x, 0.0f), t1 = fmaxf(acc.y, 0.0f);
      float t2 = fmaxf(acc.z, 0.0f), t3 = fmaxf(acc.w, 0.0f);
      #pragma unroll
      for (int c = 0; c < NC; ++c){
        float4 cv = ce4[c*(D/4) + d4];
        sims[c] = fmaf(t0, cv.x, sims[c]);
        sims[c] = fmaf(t1, cv.y, sims[c]);
        sims[c] = fmaf(t2, cv.z, sims[c]);
        sims[c] = fmaf(t3, cv.w, sims[c]);
      }
      uint4 qv = QA[d4 >> 1];
      unsigned w0 = (d4 & 1) ? qv.z : qv.x;
      unsigned w1 = (d4 & 1) ? qv.w : qv.y;
      at = fmaf(blo(w0), t0, at);
      at = fmaf(bhi(w0), t1, at);
      at = fmaf(blo(w1), t2, at);
      at = fmaf(bhi(w1), t3, at);
    }
    float best = NEGINF; int bc = 0;
    #pragma unroll
    for (int c = 0; c < NC; ++c){
      if (sims[c] > best){ best = sims[c]; bc = c; }
    }
    at *= 0.125f;
    attnE[e0] = at;
    clE[e0] = (unsigned char)bc;
    atomicAdd(&s_epc[bc], 1u);
  }

  // ---- edge 1 ----
  if (v1){
    float eav[ED] = {B0.x,B0.y,B0.z,B0.w, B1.x,B1.y,B1.z,B1.w,
                     B2.x,B2.y,B2.z,B2.w, B3.x,B3.y,B3.z,B3.w};
    float sims[NC];
    #pragma unroll
    for (int c = 0; c < NC; ++c) sims[c] = 0.0f;
    float at = qb1;
    #pragma unroll
    for (int d4 = 0; d4 < D/4; ++d4){
      float4 acc = bt4[d4];
      #pragma unroll
      for (int j = 0; j < ED; ++j){
        float4 wv = Wt4[j*(D/4) + d4];
        acc.x = fmaf(eav[j], wv.x, acc.x);
        acc.y = fmaf(eav[j], wv.y, acc.y);
        acc.z = fmaf(eav[j], wv.z, acc.z);
        acc.w = fmaf(eav[j], wv.w, acc.w);
      }
      float t0 = fmaxf(acc.x, 0.0f), t1 = fmaxf(acc.y, 0.0f);
      float t2 = fmaxf(acc.z, 0.0f), t3 = fmaxf(acc.w, 0.0f);
      #pragma unroll
      for (int c = 0; c < NC; ++c){
        float4 cv = ce4[c*(D/4) + d4];
        sims[c] = fmaf(t0, cv.x, sims[c]);
        sims[c] = fmaf(t1, cv.y, sims[c]);
        sims[c] = fmaf(t2, cv.z, sims[c]);
        sims[c] = fmaf(t3, cv.w, sims[c]);
      }
      uint4 qv = QB[d4 >> 1];
      unsigned w0 = (d4 & 1) ? qv.z : qv.x;
      unsigned w1 = (d4 & 1) ? qv.w : qv.y;
      at = fmaf(blo(w0), t0, at);
      at = fmaf(bhi(w0), t1, at);
      at = fmaf(blo(w1), t2, at);
      at = fmaf(bhi(w1), t3, at);
    }
    float best = NEGINF; int bc = 0;
    #pragma unroll
    for (int c = 0; c < NC; ++c){
      if (sims[c] > best){ best = sims[c]; bc = c; }
    }
    at *= 0.125f;
    attnE[e1] = at;
    clE[e1] = (unsigned char)bc;
    atomicAdd(&s_epc[bc], 1u);
  }

  __syncthreads();
  if (t < NC){
    unsigned v = s_epc[t];
    if (v) atomicAdd(&epc[t], v);
  }
}

// ---------------- P4: per-node softmax + T accumulation (wave per node) -----
// round-4 proven version: pass A (LDS atomics over pairS gather) + scalar
// pass B. [Round-8 lesson: LDS-block atomics ~free; scattered global atomics
// ~25-30ns each. Round-6 lesson: MFMA needs >=64-deep work per wave.]
#define EROW 20   // padded LDS row stride (floats) for ea staging
__global__ __launch_bounds__(256) void p4_node(
    const float* __restrict__ ea, const int2* __restrict__ pairS,
    const float* __restrict__ Wt, const float* __restrict__ bt,
    const float* __restrict__ attnE, const unsigned char* __restrict__ clE,
    const int* __restrict__ rowptr,
    float* __restrict__ T, float* __restrict__ S)
{
  __shared__ float s_den[4][NC];
  __shared__ int   s_cnt[4][NC];
  __shared__ float s_inv[4][NC];
  __shared__ float s_coef[4][64];
  __shared__ float s_ea[4][64][EROW];   // 20 KB
  int t = threadIdx.x, lane = t & 63, w = t >> 6;
  float wl[ED];
  #pragma unroll
  for (int j = 0; j < ED; ++j) wl[j] = Wt[j*D + lane];
  float btl = bt[lane];
  if (lane < NC){ s_den[w][lane] = 0.0f; s_cnt[w][lane] = 0; }
  int node = blockIdx.x * 4 + w;
  int start = rowptr[node], end = rowptr[node + 1];
  for (int base = start; base < end; base += 64){
    int idx = base + lane;
    if (idx < end){
      int e = pairS[idx].x;
      float ex = __expf(attnE[e]);
      int c = clE[e];
      atomicAdd(&s_den[w][c], ex);
      atomicAdd(&s_cnt[w][c], 1);
    }
  }
  if (lane < NC){
    int   cc = s_cnt[w][lane];
    float dd = s_den[w][lane];
    s_inv[w][lane] = (cc > 0) ? 1.0f / (dd * (float)cc) : 0.0f;
    float sv = (cc > 0) ? 1.0f / (float)cc : 0.0f;
    sv += __shfl_xor(sv, 1); sv += __shfl_xor(sv, 2); sv += __shfl_xor(sv, 4);
    if (lane == 0) S[node] = sv;
  }
  float Tacc = 0.0f;
  for (int base = start; base < end; base += 64){
    int idx = base + lane;
    if (idx < end){
      int e = pairS[idx].x;
      s_coef[w][lane] = __expf(attnE[e]) * s_inv[w][clE[e]];
    }
    #pragma unroll
    for (int r = 0; r < 4; ++r){
      int slot = base + r*16 + (lane >> 2);
      if (slot < end){
        int e = pairS[slot].x;
        float4 v = ((const float4*)ea)[(size_t)e*4 + (lane & 3)];
        *(float4*)&s_ea[w][slot - base][(lane & 3)*4] = v;
      }
    }
    int mm = min(64, end - base);
    for (int tt = 0; tt < mm; ++tt){
      float coef = s_coef[w][tt];
      const float4* er = (const float4*)&s_ea[w][tt][0];
      float4 e0 = er[0], e1 = er[1], e2 = er[2], e3 = er[3];
      float tfv = btl;
      tfv = fmaf(e0.x, wl[0], tfv);  tfv = fmaf(e0.y, wl[1], tfv);
      tfv = fmaf(e0.z, wl[2], tfv);  tfv = fmaf(e0.w, wl[3], tfv);
      tfv = fmaf(e1.x, wl[4], tfv);  tfv = fmaf(e1.y, wl[5], tfv);
      tfv = fmaf(e1.z, wl[6], tfv);  tfv = fmaf(e1.w, wl[7], tfv);
      tfv = fmaf(e2.x, wl[8], tfv);  tfv = fmaf(e2.y, wl[9], tfv);
      tfv = fmaf(e2.z, wl[10], tfv); tfv = fmaf(e2.w, wl[11], tfv);
      tfv = fmaf(e3.x, wl[12], tfv); tfv = fmaf(e3.y, wl[13], tfv);
      tfv = fmaf(e3.z, wl[14], tfv); tfv = fmaf(e3.w, wl[15], tfv);
      tfv = fmaxf(tfv, 0.0f);
      Tacc = fmaf(coef, tfv, Tacc);
    }
  }
  T[(size_t)node * D + lane] = Tacc;
}

// ---------------- K5: fu = relu((T@Wvo + S*bvo)/nne + bo); out = x + fu@Wu+bu
// v2: T@Wvo via LDS-broadcast (k1-v2 proven pattern) instead of 64x shfl.
// T rows staged in s_fu (reused scratch, same-wave RAW -> no barrier); fma
// accumulation order i ascending = bit-identical to the shfl version.
__global__ __launch_bounds__(256) void k5_out(
    const float* __restrict__ x, const float* __restrict__ T, const float* __restrict__ S,
    const float* __restrict__ Wvo, const float* __restrict__ bvo,
    const unsigned* __restrict__ WuP, const float* __restrict__ bu,
    const float* __restrict__ bo, const unsigned* __restrict__ epc,
    float* __restrict__ out)
{
  __shared__ unsigned sWuP[8192];   // 32 KB packed bf16 Wu
  __shared__ float s_fu[16*64];     // 4 KB (stages T, then holds fu)
  int t = threadIdx.x;
  #pragma unroll
  for (int i = 0; i < 8; ++i)
    ((uint4*)sWuP)[t + 256*i] = ((const uint4*)WuP)[t + 256*i];
  int lane = t & 63;
  int wg = __builtin_amdgcn_readfirstlane(t >> 6);
  int n0 = blockIdx.x * 16 + wg * 4;
  float nne = 0.0f;
  #pragma unroll
  for (int c = 0; c < NC; ++c) nne += (epc[c] > 0u) ? 1.0f : 0.0f;
  float inv = 1.0f / fmaxf(nne, 1.0f);
  // stage this wave's 4 T rows into s_fu (only this wave reads them back)
  s_fu[(wg*4+0)*64 + lane] = T[(size_t)(n0+0)*D + lane];
  s_fu[(wg*4+1)*64 + lane] = T[(size_t)(n0+1)*D + lane];
  s_fu[(wg*4+2)*64 + lane] = T[(size_t)(n0+2)*D + lane];
  s_fu[(wg*4+3)*64 + lane] = T[(size_t)(n0+3)*D + lane];
  float bvl = bvo[lane], bol = bo[lane];
  float f0 = S[n0+0]*bvl, f1 = S[n0+1]*bvl, f2 = S[n0+2]*bvl, f3 = S[n0+3]*bvl;
  const float4* t0p = (const float4*)&s_fu[(wg*4+0)*64];
  const float4* t1p = (const float4*)&s_fu[(wg*4+1)*64];
  const float4* t2p = (const float4*)&s_fu[(wg*4+2)*64];
  const float4* t3p = (const float4*)&s_fu[(wg*4+3)*64];
  #pragma unroll 4
  for (int i4 = 0; i4 < 16; ++i4){
    float4 v0 = t0p[i4], v1 = t1p[i4], v2 = t2p[i4], v3 = t3p[i4];
    float m0 = Wvo[(4*i4+0)*64 + lane];   // L1-resident (16 KB), coalesced
    float m1 = Wvo[(4*i4+1)*64 + lane];
    float m2 = Wvo[(4*i4+2)*64 + lane];
    float m3 = Wvo[(4*i4+3)*64 + lane];
    f0 = fmaf(v0.x,m0,f0); f0 = fmaf(v0.y,m1,f0); f0 = fmaf(v0.z,m2,f0); f0 = fmaf(v0.w,m3,f0);
    f1 = fmaf(v1.x,m0,f1); f1 = fmaf(v1.y,m1,f1); f1 = fmaf(v1.z,m2,f1); f1 = fmaf(v1.w,m3,f1);
    f2 = fmaf(v2.x,m0,f2); f2 = fmaf(v2.y,m1,f2); f2 = fmaf(v2.z,m2,f2); f2 = fmaf(v2.w,m3,f2);
    f3 = fmaf(v3.x,m0,f3); f3 = fmaf(v3.y,m1,f3); f3 = fmaf(v3.z,m2,f3); f3 = fmaf(v3.w,m3,f3);
  }
  f0 = fmaxf(f0*inv + bol, 0.0f);
  f1 = fmaxf(f1*inv + bol, 0.0f);
  f2 = fmaxf(f2*inv + bol, 0.0f);
  f3 = fmaxf(f3*inv + bol, 0.0f);
  s_fu[(wg*4+0)*64 + lane] = f0;
  s_fu[(wg*4+1)*64 + lane] = f1;
  s_fu[(wg*4+2)*64 + lane] = f2;
  s_fu[(wg*4+3)*64 + lane] = f3;
  __syncthreads();
  float4 bu4 = ((const float4*)bu)[lane];
  float4 o0 = ((const float4*)(x + (size_t)(n0+0)*INCH))[lane];
  float4 o1 = ((const float4*)(x + (size_t)(n0+1)*INCH))[lane];
  float4 o2 = ((const float4*)(x + (size_t)(n0+2)*INCH))[lane];
  float4 o3 = ((const float4*)(x + (size_t)(n0+3)*INCH))[lane];
  o0.x += bu4.x; o0.y += bu4.y; o0.z += bu4.z; o0.w += bu4.w;
  o1.x += bu4.x; o1.y += bu4.y; o1.z += bu4.z; o1.w += bu4.w;
  o2.x += bu4.x; o2.y += bu4.y; o2.z += bu4.z; o2.w += bu4.w;
  o3.x += bu4.x; o3.y += bu4.y; o3.z += bu4.z; o3.w += bu4.w;
  const float2* fu2 = (const float2*)s_fu;
  #pragma unroll 4
  for (int d2 = 0; d2 < 32; ++d2){
    uint4 wp = *(const uint4*)&sWuP[d2*256 + lane*4];
    float4 wlv = { blo(wp.x), blo(wp.y), blo(wp.z), blo(wp.w) };
    float4 wh  = { bhi(wp.x), bhi(wp.y), bhi(wp.z), bhi(wp.w) };
    float2 g0 = fu2[(wg*4+0)*32 + d2];
    float2 g1 = fu2[(wg*4+1)*32 + d2];
    float2 g2 = fu2[(wg*4+2)*32 + d2];
    float2 g3 = fu2[(wg*4+3)*32 + d2];
    o0.x = fmaf(g0.x, wlv.x, o0.x); o0.y = fmaf(g0.x, wlv.y, o0.y);
    o0.z = fmaf(g0.x, wlv.z, o0.z); o0.w = fmaf(g0.x, wlv.w, o0.w);
    o0.x = fmaf(g0.y, wh.x, o0.x);  o0.y = fmaf(g0.y, wh.y, o0.y);
    o0.z = fmaf(g0.y, wh.z, o0.z);  o0.w = fmaf(g0.y, wh.w, o0.w);
    o1.x = fmaf(g1.x, wlv.x, o1.x); o1.y = fmaf(g1.x, wlv.y, o1.y);
    o1.z = fmaf(g1.x, wlv.z, o1.z); o1.w = fmaf(g1.x, wlv.w, o1.w);
    o1.x = fmaf(g1.y, wh.x, o1.x);  o1.y = fmaf(g1.y, wh.y, o1.y);
    o1.z = fmaf(g1.y, wh.z, o1.z);  o1.w = fmaf(g1.y, wh.w, o1.w);
    o2.x = fmaf(g2.x, wlv.x, o2.x); o2.y = fmaf(g2.x, wlv.y, o2.y);
    o2.z = fmaf(g2.x, wlv.z, o2.z); o2.w = fmaf(g2.x, wlv.w, o2.w);
    o2.x = fmaf(g2.y, wh.x, o2.x);  o2.y = fmaf(g2.y, wh.y, o2.y);
    o2.z = fmaf(g2.y, wh.z, o2.z);  o2.w = fmaf(g2.y, wh.w, o2.w);
    o3.x = fmaf(g3.x, wlv.x, o3.x); o3.y = fmaf(g3.x, wlv.y, o3.y);
    o3.z = fmaf(g3.x, wlv.z, o3.z); o3.w = fmaf(g3.x, wlv.w, o3.w);
    o3.x = fmaf(g3.y, wh.x, o3.x);  o3.y = fmaf(g3.y, wh.y, o3.y);
    o3.z = fmaf(g3.y, wh.z, o3.z);  o3.w = fmaf(g3.y, wh.w, o3.w);
  }
  ((float4*)(out + (size_t)(n0+0)*INCH))[lane] = o0;
  ((float4*)(out + (size_t)(n0+1)*INCH))[lane] = o1;
  ((float4*)(out + (size_t)(n0+2)*INCH))[lane] = o2;
  ((float4*)(out + (size_t)(n0+3)*INCH))[lane] = o3;
}

extern "C" void kernel_launch(void* const* d_in, const int* in_sizes, int n_in,
                              void* d_out, int out_size, void* d_ws, size_t ws_size,
                              hipStream_t stream)
{
  const float* x  = (const float*)d_in[0];
  const float* ea = (const float*)d_in[1];
  const int* eidx = (const int*)d_in[2];      // [2,E]; row 0 = src
  const float* Wd = (const float*)d_in[3];  const float* bd = (const float*)d_in[4];
  const float* Wu = (const float*)d_in[5];  const float* bu = (const float*)d_in[6];
  const float* Wt = (const float*)d_in[7];  const float* bt = (const float*)d_in[8];
  const float* Wq = (const float*)d_in[9];  const float* bq = (const float*)d_in[10];
  const float* Wk = (const float*)d_in[11]; const float* bk = (const float*)d_in[12];
  const float* Wv = (const float*)d_in[13]; const float* bv = (const float*)d_in[14];
  const float* ce = (const float*)d_in[15];
  const float* Wo = (const float*)d_in[16]; const float* bo = (const float*)d_in[17];
  float* out = (float*)d_out;

  size_t need = 0;
  need += (size_t)NN*4;          // cnt
  need += (size_t)NN*4;          // fill
  need += 64;                    // epc
  size_t zbytes = need;          // zero region
  need += (size_t)(NN+4)*4;      // rowptr
  need += 1024;                  // bsum
  need += (size_t)NN*D*2;        // qkH (bf16)
  need += (size_t)NN*4;          // qb
  need += (size_t)EE*8;          // pairS
  need += (size_t)EE*4;          // attnE
  need += (size_t)EE;            // clE
  need += 16;                    // align
  need += (size_t)NN*D*4;        // T
  need += (size_t)NN*4;          // S
  need += 256 + 256 + 16 + 4096*4 + 256;   // cvec,u,s0,Wvo,bvo
  need += 8192*4 + 8192*4;       // WdTP, WuP
  need += 2048*4 + 2048*4;       // MThP, MTlP
  need += 1024*4 + 1024*4;       // WtTPh, WtTPl

  char* w = (char*)d_ws;
  if (ws_size < need){
    void* p = nullptr;
    hipGetSymbolAddress(&p, HIP_SYMBOL(g_ws));
    w = (char*)p;
  }
  size_t off = 0;
  int*      cnt    = (int*)(w + off);      off += (size_t)NN*4;
  int*      fill   = (int*)(w + off);      off += (size_t)NN*4;
  unsigned* epc    = (unsigned*)(w + off); off += 64;
  int*      rowptr = (int*)(w + off);      off += (size_t)(NN+4)*4;
  int*      bsum   = (int*)(w + off);      off += 1024;
  unsigned short* qkH = (unsigned short*)(w + off); off += (size_t)NN*D*2;
  float*    qb     = (float*)(w + off);    off += (size_t)NN*4;
  int2*     pairS  = (int2*)(w + off);     off += (size_t)EE*8;
  float*    attnE  = (float*)(w + off);    off += (size_t)EE*4;
  unsigned char* clE = (unsigned char*)(w + off); off += (size_t)EE;
  off = (off + 15) & ~(size_t)15;
  float*    T      = (float*)(w + off);    off += (size_t)NN*D*4;
  float*    S      = (float*)(w + off);    off += (size_t)NN*4;
  float*    cvec   = (float*)(w + off);    off += 256;
  float*    u      = (float*)(w + off);    off += 256;
  float*    s0     = (float*)(w + off);    off += 16;
  float*    Wvo    = (float*)(w + off);    off += 4096*4;
  float*    bvo    = (float*)(w + off);    off += 256;
  unsigned* WdTP   = (unsigned*)(w + off); off += 8192*4;
  unsigned* WuP    = (unsigned*)(w + off); off += 8192*4;
  unsigned* MThP   = (unsigned*)(w + off); off += 2048*4;
  unsigned* MTlP   = (unsigned*)(w + off); off += 2048*4;
  unsigned* WtTPh  = (unsigned*)(w + off); off += 1024*4;
  unsigned* WtTPl  = (unsigned*)(w + off); off += 1024*4;

  int zwords = (int)(zbytes / 4);
  Adapter_30872224923942_kernel<<<dim3(128), dim3(256), 0, stream>>>((unsigned*)w, zwords);
  kpre<<<dim3(28), dim3(256), 0, stream>>>(Wq, bq, Wk, bk, Wv, bv, Wo, Wd, Wu, Wt,
                                           cvec, u, s0, Wvo, bvo, WdTP, WuP,
                                           MThP, MTlP, WtTPh, WtTPl);
  p1_hist<<<dim3(EE/256), dim3(256), 0, stream>>>(eidx, cnt);
  s1_scan<<<dim3(NB), dim3(256), 0, stream>>>(cnt, rowptr, bsum);
  s2_scan<<<dim3(1),  dim3(256), 0, stream>>>(bsum);
  s3_add <<<dim3(NB), dim3(256), 0, stream>>>(rowptr, bsum);
  p2_build<<<dim3(EE/256), dim3(256), 0, stream>>>(eidx, rowptr, fill, pairS);
  k1_node<<<dim3((NN + 63)/64), dim3(256), 0, stream>>>(x, WdTP, bd, MThP, MTlP,
                                                        cvec, u, s0, qkH, qb);
  p3_edge<<<dim3((EE + 511)/512), dim3(256), 0, stream>>>(ea, eidx, Wt, bt, ce, qkH, qb,
                                                          attnE, clE, epc);
  p4_node<<<dim3(NN/4), dim3(256), 0, stream>>>(ea, pairS, Wt, bt, attnE, clE, rowptr, T, S);
  k5_out <<<dim3(NN/16), dim3(256), 0, stream>>>(x, T, S, Wvo, bvo, WuP, bu, bo, epc, out);
}